// Round 10
// baseline (108.386 us; speedup 1.0000x reference)
//
#include <hip/hip_runtime.h>
#include <math.h>

typedef unsigned int u32;
typedef unsigned short u16;
typedef unsigned char u8;
typedef int i32x4 __attribute__((ext_vector_type(4)));
typedef int i32x16 __attribute__((ext_vector_type(16)));

#if __has_builtin(__builtin_amdgcn_mfma_i32_32x32x32_i8)
#define HAS_MFMA_I8 1
#else
#define HAS_MFMA_I8 0
#endif

__device__ __forceinline__ u32 sad8(u32 a, u32 b, u32 c){
#if __has_builtin(__builtin_amdgcn_sad_u8)
    return __builtin_amdgcn_sad_u8(a, b, c);
#else
    u32 s = c;
#pragma unroll
    for (int k = 0; k < 4; ++k){
        int av = (int)((a >> (8*k)) & 255u), bv = (int)((b >> (8*k)) & 255u);
        s += (u32)(av > bv ? av - bv : bv - av);
    }
    return s;
#endif
}

__device__ __forceinline__ u32 hsum16(u32 x, u32 c){ return c + (x & 0xFFFFu) + (x >> 16); }

__device__ __forceinline__ int sq4(u32 a, int c){   // sum of squares of 4 s8 bytes (a is s8-packed)
#if __has_builtin(__builtin_amdgcn_sdot4)
    return __builtin_amdgcn_sdot4((int)a, (int)a, c, false);
#else
    int s = c;
#pragma unroll
    for (int k = 0; k < 4; ++k){
        int av = (int)(signed char)((a >> (8*k)) & 255u);
        s += av * av;
    }
    return s;
#endif
}

#if !HAS_MFMA_I8
__device__ __forceinline__ int sdot4m(u32 a, u32 b, int c){
#if __has_builtin(__builtin_amdgcn_sdot4)
    return __builtin_amdgcn_sdot4((int)a, (int)b, c, false);
#else
    int s = c;
#pragma unroll
    for (int k = 0; k < 4; ++k){
        int av = (int)(signed char)((a >> (8*k)) & 255u);
        int bv = (int)(signed char)((b >> (8*k)) & 255u);
        s += av * bv;
    }
    return s;
#endif
}
#endif

__device__ __forceinline__ u32 q4(float4 v){   // 4 floats -> 4 u8 (round(16x)+128), packed
    u32 a =  ((u32)fmaf(v.x, 16.f, 128.5f) & 255u);
    a |= ((u32)fmaf(v.y, 16.f, 128.5f) & 255u) << 8;
    a |= ((u32)fmaf(v.z, 16.f, 128.5f) & 255u) << 16;
    a |= ((u32)fmaf(v.w, 16.f, 128.5f) & 255u) << 24;
    return a;
}

// R10: single kernel. 512 blocks (32 bn x 16 bm), tile 32n x 64m, 512 thr = 8 waves.
// Each block quantizes its OWN 96 rows from f32 (L2-resident inputs) into a
// full-K u8 LDS tile [96 rows][33 units of 16B] (unit 32 = pad; bank group
// (row+unit)&7). Norms computed in-block via sdot4 on the same staged bytes
// (exact ints, deterministic). Downstream = R9 verified: sad 8n x 4m micro,
// i8 MFMA dp (waves 0-3, 2 khalf x 2 mtile), l2^2 = nz + np - 2dp exact.
// LDS 52.6 KB; epilogue overlays staging; norm partials live above staging.
#define L1S 520
__global__ __launch_bounds__(512, 4) void fused_kernel(const float* __restrict__ z,
                                                       const float* __restrict__ zpr,
                                                       float* __restrict__ out){
    __shared__ u32 smem[13152];
    // words: staging [96][132] = 12672 | nparts [96][4] @12672 | nfinal [96] @13056
    float* nparts = (float*)(smem + 12672);
    float* nfinal = (float*)(smem + 13056);

    const int t = threadIdx.x;
    const int lane = t & 63;
    const int w = t >> 6;
    const int bn = blockIdx.x & 31;
    const int bm = blockIdx.x >> 5;
    const int n_base = bn*32, m_base = bm*64;

    // ---- stage: load f32, quantize, write u8 tile ----
#pragma unroll
    for (int j = 0; j < 6; ++j){
        const int id = j*512 + t;
        const int r = id >> 5, u = id & 31;
        const float* src = (r < 32) ? (z + (size_t)(n_base + r)*512)
                                    : (zpr + (size_t)(m_base + r - 32)*512);
        const float4* s4 = (const float4*)(src + u*16);
        uint4 qv = make_uint4(q4(s4[0]), q4(s4[1]), q4(s4[2]), q4(s4[3]));
        *(uint4*)(smem + (r*33 + u)*4) = qv;
    }

    const int tn = lane & 3, tm = lane >> 2;
    u32 acc[8][4];
#pragma unroll
    for (int i = 0; i < 8; ++i)
#pragma unroll
        for (int j = 0; j < 4; ++j) acc[i][j] = 0u;

#if HAS_MFMA_I8
    i32x16 dpacc = (i32x16)(0);
    const int mt = w & 1;          // m-tile (32 cols) for waves 0-3
    const int kh = w >> 1;         // k-half for waves 0-3
    const int arow = lane & 31;
    const int brow = 32 + mt*32 + (lane & 31);
    const int o1 = lane >> 5;
#else
    int dpa[8][4];
#pragma unroll
    for (int i = 0; i < 8; ++i)
#pragma unroll
        for (int j = 0; j < 4; ++j) dpa[i][j] = 0;
#endif

    __syncthreads();   // barrier #1: tile staged (register-tracked ds_writes)

#if HAS_MFMA_I8
    if (w < 4){
#pragma unroll
        for (int s = 0; s < 8; ++s){
            const int ua = kh*16 + s*2 + o1;   // 16B unit within row
#pragma unroll
            for (int dummy = 0; dummy < 1; ++dummy){}
            uint4 a = *(const uint4*)(smem + (arow*33 + ua)*4);
            uint4 b = *(const uint4*)(smem + (brow*33 + ua)*4);
            uint4 ax = make_uint4(a.x^0x80808080u, a.y^0x80808080u, a.z^0x80808080u, a.w^0x80808080u);
            uint4 bx = make_uint4(b.x^0x80808080u, b.y^0x80808080u, b.z^0x80808080u, b.w^0x80808080u);
            dpacc = __builtin_amdgcn_mfma_i32_32x32x32_i8(__builtin_bit_cast(i32x4, ax),
                                                          __builtin_bit_cast(i32x4, bx),
                                                          dpacc, 0, 0, 0);
        }
    }
#endif

    // ---- sad hot loop: wave w's k-slice [64w, 64w+64) = units 4w..4w+3 ----
#pragma unroll
    for (int c = 0; c < 4; ++c){
        const int uu = 4*w + c;
        uint4 av[8], bv[4];
#pragma unroll
        for (int i = 0; i < 8; ++i)
            av[i] = *(const uint4*)(smem + ((tn + 4*i)*33 + uu)*4);
#pragma unroll
        for (int j2 = 0; j2 < 4; ++j2)
            bv[j2] = *(const uint4*)(smem + ((32 + tm + 16*j2)*33 + uu)*4);
#pragma unroll
        for (int i = 0; i < 8; ++i)
#pragma unroll
            for (int j2 = 0; j2 < 4; ++j2){
                u32 s = acc[i][j2];
                s = sad8(av[i].x, bv[j2].x, s);
                s = sad8(av[i].y, bv[j2].y, s);
                s = sad8(av[i].z, bv[j2].z, s);
                s = sad8(av[i].w, bv[j2].w, s);
                acc[i][j2] = s;
#if !HAS_MFMA_I8
                int d = dpa[i][j2];
                d = sdot4m(av[i].x^0x80808080u, bv[j2].x^0x80808080u, d);
                d = sdot4m(av[i].y^0x80808080u, bv[j2].y^0x80808080u, d);
                d = sdot4m(av[i].z^0x80808080u, bv[j2].z^0x80808080u, d);
                d = sdot4m(av[i].w^0x80808080u, bv[j2].w^0x80808080u, d);
                dpa[i][j2] = d;
#endif
            }
    }

    // ---- norm partials: threads 128..511, one (row, quarter) each ----
    if (t >= 128){
        const int row = (t - 128) >> 2;
        const int qq  = (t - 128) & 3;
        int s = 0;
#pragma unroll
        for (int j = 0; j < 8; ++j){
            uint4 x = *(const uint4*)(smem + (row*33 + qq*8 + j)*4);
            s = sq4(x.x^0x80808080u, s);
            s = sq4(x.y^0x80808080u, s);
            s = sq4(x.z^0x80808080u, s);
            s = sq4(x.w^0x80808080u, s);
        }
        nparts[row*4 + qq] = (float)s;
    }
    __syncthreads();   // barrier #2: all tile reads + norm partials done

    // ---- epilogue (overlays staging region, words 0..12480) ----
    u16*   l1b  = (u16*)smem;                  // [32 n][520] u16
    float* dpbA = (float*)(smem + 8320);       // [32][65]
    float* dpbB = (float*)(smem + 10400);      // [32][65]

#pragma unroll
    for (int i = 0; i < 8; ++i)
#pragma unroll
        for (int j = 0; j < 4; ++j)
            l1b[(tn + 4*i)*L1S + (tm + 16*j)*8 + w] = (u16)acc[i][j];

#if HAS_MFMA_I8
    if (w < 4){
        float* dpb = kh ? dpbB : dpbA;
        const int mcol = mt*32 + (lane & 31);
#pragma unroll
        for (int reg = 0; reg < 16; ++reg){
            const int n = (reg & 3) + 8*(reg >> 2) + 4*(lane >> 5);
            dpb[n*65 + mcol] = (float)dpacc[reg];
        }
    }
#endif
    if (t < 96){
        float4 p = *(const float4*)&nparts[t*4];
        nfinal[t] = p.x + p.y + p.z + p.w;
    }
    __syncthreads();   // barrier #3

    const int m  = t >> 3;
    const int n0 = 4*(t & 7);
    float4 nz4 = *(const float4*)&nfinal[n0];
    const float np = nfinal[32 + m];
    const float nzv[4] = {nz4.x, nz4.y, nz4.z, nz4.w};

    float l1q[4], dpq[4];
#pragma unroll
    for (int i = 0; i < 4; ++i){
        const int n = n0 + i;
        uint4 lp = *(const uint4*)&l1b[n*L1S + m*8];
        u32 s = hsum16(lp.x, 0u); s = hsum16(lp.y, s);
        s = hsum16(lp.z, s);      s = hsum16(lp.w, s);
        l1q[i] = (float)s;
#if HAS_MFMA_I8
        dpq[i] = dpbA[n*65 + m] + dpbB[n*65 + m];
#else
        dpq[i] = 0.f;
#endif
    }

#if !HAS_MFMA_I8
    {
        float* dpf = (float*)(smem + 0);   // reuse; 2048*2 words fits under 12480
#pragma unroll
        for (int ph = 0; ph < 4; ++ph){
            __syncthreads();
            if ((w >> 1) == ph){
#pragma unroll
                for (int i = 0; i < 8; ++i)
#pragma unroll
                    for (int j = 0; j < 4; ++j)
                        dpf[((tn + 4*i)*64 + tm + 16*j)*2 + (w & 1)] = (float)dpa[i][j];
            }
            __syncthreads();
#pragma unroll
            for (int i = 0; i < 4; ++i){
                const int cell = (n0 + i)*64 + m;
                dpq[i] += dpf[cell*2] + dpf[cell*2 + 1];
            }
        }
    }
#endif

    float ov[12];
#pragma unroll
    for (int i = 0; i < 4; ++i){
        const float l2q = nzv[i] + np - 2.f*dpq[i];
        ov[3*i]     = l1q[i] * 0.0625f;
        ov[3*i + 1] = sqrtf(fmaxf(l2q, 0.f)) * 0.0625f;
        ov[3*i + 2] = dpq[i] * 0.00390625f;
    }
    float4* op = (float4*)(out + (((size_t)(m_base + m))*1024 + n_base + n0)*3);
    op[0] = make_float4(ov[0], ov[1], ov[2],  ov[3]);
    op[1] = make_float4(ov[4], ov[5], ov[6],  ov[7]);
    op[2] = make_float4(ov[8], ov[9], ov[10], ov[11]);
}

extern "C" void kernel_launch(void* const* d_in, const int* in_sizes, int n_in,
                              void* d_out, int out_size, void* d_ws, size_t ws_size,
                              hipStream_t stream) {
    const float* z   = (const float*)d_in[0];
    const float* zpr = (const float*)d_in[1];
    float* out = (float*)d_out;
    fused_kernel<<<512, 512, 0, stream>>>(z, zpr, out);
}

// Round 11
// 99.048 us; speedup vs baseline: 1.0943x; 1.0943x over previous
//
#include <hip/hip_runtime.h>
#include <math.h>

typedef unsigned int u32;
typedef unsigned short u16;
typedef unsigned char u8;
typedef int i32x4 __attribute__((ext_vector_type(4)));
typedef int i32x16 __attribute__((ext_vector_type(16)));

#if __has_builtin(__builtin_amdgcn_mfma_i32_32x32x32_i8)
#define HAS_MFMA_I8 1
#else
#define HAS_MFMA_I8 0
#endif

__device__ __forceinline__ u32 sad8(u32 a, u32 b, u32 c){
#if __has_builtin(__builtin_amdgcn_sad_u8)
    return __builtin_amdgcn_sad_u8(a, b, c);
#else
    u32 s = c;
#pragma unroll
    for (int k = 0; k < 4; ++k){
        int av = (int)((a >> (8*k)) & 255u), bv = (int)((b >> (8*k)) & 255u);
        s += (u32)(av > bv ? av - bv : bv - av);
    }
    return s;
#endif
}

__device__ __forceinline__ u32 hsum16(u32 x, u32 c){ return c + (x & 0xFFFFu) + (x >> 16); }

#if !HAS_MFMA_I8
__device__ __forceinline__ int sdot4m(u32 a, u32 b, int c){
#if __has_builtin(__builtin_amdgcn_sdot4)
    return __builtin_amdgcn_sdot4((int)a, (int)b, c, false);
#else
    int s = c;
#pragma unroll
    for (int k = 0; k < 4; ++k){
        int av = (int)(signed char)((a >> (8*k)) & 255u);
        int bv = (int)(signed char)((b >> (8*k)) & 255u);
        s += av * bv;
    }
    return s;
#endif
}
#endif

// ---- prep: q8[row][512] = round(16x)+128 (u8); norms[row] = sum s8^2 (exact int in f32)
__global__ __launch_bounds__(512) void prep_kernel(const float* __restrict__ z,
                                                   const float* __restrict__ zpr,
                                                   u8* __restrict__ q8,
                                                   float* __restrict__ norms){
    const int row  = blockIdx.x*8 + (threadIdx.x >> 6);
    const int lane = threadIdx.x & 63;
    const float* src = (row < 1024) ? (z + (size_t)row*512) : (zpr + (size_t)(row-1024)*512);
    float4 v0 = ((const float4*)src)[2*lane];
    float4 v1 = ((const float4*)src)[2*lane + 1];
    float xs[8] = {v0.x,v0.y,v0.z,v0.w,v1.x,v1.y,v1.z,v1.w};
    u32 b0 = 0, b1 = 0; float s = 0.f;
#pragma unroll
    for (int k = 0; k < 4; ++k){
        u32 qa = (u32)fmaf(xs[k],   16.f, 128.5f) & 255u;
        u32 qb = (u32)fmaf(xs[4+k], 16.f, 128.5f) & 255u;
        b0 |= qa << (8*k);  b1 |= qb << (8*k);
        int sa = (int)qa - 128, sb = (int)qb - 128;
        s += (float)(sa*sa + sb*sb);
    }
    ((uint2*)(q8 + (size_t)row*512))[lane] = make_uint2(b0, b1);
#pragma unroll
    for (int off = 32; off > 0; off >>= 1) s += __shfl_down(s, off);
    if (lane == 0) norms[row] = s;
}

// ---- main (R11 = verified R9 + swizzled staging + 3 blocks/CU) ----
// 512 blocks (32 bn x 16 bm), tile 32n x 64m, 512 thr = 8 waves.
// Staging layout: [96 rows] x [32 units of 16B], word(row,unit,wd) =
// row*128 + ((unit+row)&31)*4 + wd  -> 48 KB, no pad. Rotation makes all hot
// ds_read_b128 conflict-free (consecutive rows -> consecutive bank quads).
// Wave w's k-slice = units [4w, 4w+4). Single phase: uint4 load + ds_write
// (register-tracked deps -> no R8 DMA race), barrier, compute, barrier,
// epilogue overlay. launch_bounds(512,6): 49.9 KB LDS x3 = 149.8 <= 160 KB,
// VGPR 64+16 AGPR = 80 <= 85 cap -> 6 waves/SIMD.
#define L1S 520
__global__ __launch_bounds__(512, 6) void fused_kernel(const u8* __restrict__ q8,
                                                       const float* __restrict__ norms,
                                                       float* __restrict__ out){
    __shared__ u32 smem[12480];   // 49.9 KB: staging 12288 w | epilogue overlay 12480 w
    const int t = threadIdx.x;
    const int lane = t & 63;
    const int w = t >> 6;
    const int bn = blockIdx.x & 31;
    const int bm = blockIdx.x >> 5;
    const int n_base = bn*32, m_base = bm*64;

    // ---- stage: wave w's k-slice [64w, 64w+64), 96 rows (32 z + 64 zpr) ----
    {
        const int c = lane & 3;              // 16B column within slice
        const int r4 = lane >> 2;            // row within 16-row group
#pragma unroll
        for (int j = 0; j < 6; ++j){
            const int rt = j*16 + r4;        // 0..95
            const int grow = (rt < 32) ? (n_base + rt) : (1024 + m_base + rt - 32);
            uint4 v = *(const uint4*)(q8 + (size_t)grow*512 + 64*w + 16*c);
            *(uint4*)(smem + rt*128 + (((4*w + c) + rt) & 31)*4) = v;
        }
    }

    const int tn = lane & 3, tm = lane >> 2;
    u32 acc[8][4];
#pragma unroll
    for (int i = 0; i < 8; ++i)
#pragma unroll
        for (int j = 0; j < 4; ++j) acc[i][j] = 0u;

#if HAS_MFMA_I8
    i32x16 dpacc = (i32x16)(0);
    const int mt = w & 1;          // m-tile (32 cols) for waves 0-3
    const int kh = w >> 1;         // k-half for waves 0-3
    const int arow = lane & 31;
    const int brow = 32 + mt*32 + (lane & 31);
    const int o1 = lane >> 5;
#else
    int dpa[8][4];
#pragma unroll
    for (int i = 0; i < 8; ++i)
#pragma unroll
        for (int j = 0; j < 4; ++j) dpa[i][j] = 0;
#endif

    __syncthreads();   // barrier #1: tile staged

#if HAS_MFMA_I8
    if (w < 4){
#pragma unroll
        for (int s = 0; s < 8; ++s){
            const int ua = kh*16 + s*2 + o1;   // 16B unit (k = 16*ua + byte)
            uint4 a = *(const uint4*)(smem + arow*128 + ((ua + arow) & 31)*4);
            uint4 b = *(const uint4*)(smem + brow*128 + ((ua + brow) & 31)*4);
            uint4 ax = make_uint4(a.x^0x80808080u, a.y^0x80808080u, a.z^0x80808080u, a.w^0x80808080u);
            uint4 bx = make_uint4(b.x^0x80808080u, b.y^0x80808080u, b.z^0x80808080u, b.w^0x80808080u);
            dpacc = __builtin_amdgcn_mfma_i32_32x32x32_i8(__builtin_bit_cast(i32x4, ax),
                                                          __builtin_bit_cast(i32x4, bx),
                                                          dpacc, 0, 0, 0);
        }
    }
#endif

    // ---- sad hot loop: wave w's 64 k (units 4w..4w+3), 8n x 4m micro ----
#pragma unroll
    for (int c2 = 0; c2 < 4; ++c2){
        const int uu = 4*w + c2;
        uint4 av[8], bv[4];
#pragma unroll
        for (int i = 0; i < 8; ++i){
            const int r = tn + 4*i;
            av[i] = *(const uint4*)(smem + r*128 + ((uu + r) & 31)*4);
        }
#pragma unroll
        for (int j2 = 0; j2 < 4; ++j2){
            const int r = 32 + tm + 16*j2;
            bv[j2] = *(const uint4*)(smem + r*128 + ((uu + r) & 31)*4);
        }
#pragma unroll
        for (int i = 0; i < 8; ++i)
#pragma unroll
            for (int j2 = 0; j2 < 4; ++j2){
                u32 s = acc[i][j2];
                s = sad8(av[i].x, bv[j2].x, s);
                s = sad8(av[i].y, bv[j2].y, s);
                s = sad8(av[i].z, bv[j2].z, s);
                s = sad8(av[i].w, bv[j2].w, s);
                acc[i][j2] = s;
#if !HAS_MFMA_I8
                int d = dpa[i][j2];
                d = sdot4m(av[i].x^0x80808080u, bv[j2].x^0x80808080u, d);
                d = sdot4m(av[i].y^0x80808080u, bv[j2].y^0x80808080u, d);
                d = sdot4m(av[i].z^0x80808080u, bv[j2].z^0x80808080u, d);
                d = sdot4m(av[i].w^0x80808080u, bv[j2].w^0x80808080u, d);
                dpa[i][j2] = d;
#endif
            }
    }
    __syncthreads();   // barrier #2: all reads done; staging region dead

    // ---- epilogue (overlays staging) ----
    u16*   l1b  = (u16*)smem;                  // [32 n][520] u16
    float* dpbA = (float*)(smem + 8320);       // [32][65]
    float* dpbB = (float*)(smem + 10400);      // [32][65]

#pragma unroll
    for (int i = 0; i < 8; ++i)
#pragma unroll
        for (int j = 0; j < 4; ++j)
            l1b[(tn + 4*i)*L1S + (tm + 16*j)*8 + w] = (u16)acc[i][j];

#if HAS_MFMA_I8
    if (w < 4){
        float* dpb = kh ? dpbB : dpbA;
        const int mcol = mt*32 + (lane & 31);
#pragma unroll
        for (int reg = 0; reg < 16; ++reg){
            const int n = (reg & 3) + 8*(reg >> 2) + 4*(lane >> 5);
            dpb[n*65 + mcol] = (float)dpacc[reg];
        }
    }
#endif
    __syncthreads();

    const int m  = t >> 3;
    const int n0 = 4*(t & 7);
    float4 nz4 = *(const float4*)&norms[n_base + n0];
    const float np = norms[1024 + m_base + m];
    const float nzv[4] = {nz4.x, nz4.y, nz4.z, nz4.w};

    float l1q[4], dpq[4];
#pragma unroll
    for (int i = 0; i < 4; ++i){
        const int n = n0 + i;
        uint4 lp = *(const uint4*)&l1b[n*L1S + m*8];
        u32 s = hsum16(lp.x, 0u); s = hsum16(lp.y, s);
        s = hsum16(lp.z, s);      s = hsum16(lp.w, s);
        l1q[i] = (float)s;
#if HAS_MFMA_I8
        dpq[i] = dpbA[n*65 + m] + dpbB[n*65 + m];
#else
        dpq[i] = 0.f;
#endif
    }

#if !HAS_MFMA_I8
    {
        float* dpf = (float*)(smem + 8320);   // [2048][2] words -> ends 12416 <= 12480
#pragma unroll
        for (int ph = 0; ph < 4; ++ph){
            __syncthreads();
            if ((w >> 1) == ph){
#pragma unroll
                for (int i = 0; i < 8; ++i)
#pragma unroll
                    for (int j = 0; j < 4; ++j)
                        dpf[((tn + 4*i)*64 + tm + 16*j)*2 + (w & 1)] = (float)dpa[i][j];
            }
            __syncthreads();
#pragma unroll
            for (int i = 0; i < 4; ++i){
                const int cell = (n0 + i)*64 + m;
                dpq[i] += dpf[cell*2] + dpf[cell*2 + 1];
            }
        }
    }
#endif

    float ov[12];
#pragma unroll
    for (int i = 0; i < 4; ++i){
        const float l2q = nzv[i] + np - 2.f*dpq[i];
        ov[3*i]     = l1q[i] * 0.0625f;
        ov[3*i + 1] = sqrtf(fmaxf(l2q, 0.f)) * 0.0625f;
        ov[3*i + 2] = dpq[i] * 0.00390625f;
    }
    float4* op = (float4*)(out + (((size_t)(m_base + m))*1024 + n_base + n0)*3);
    op[0] = make_float4(ov[0], ov[1], ov[2],  ov[3]);
    op[1] = make_float4(ov[4], ov[5], ov[6],  ov[7]);
    op[2] = make_float4(ov[8], ov[9], ov[10], ov[11]);
}

extern "C" void kernel_launch(void* const* d_in, const int* in_sizes, int n_in,
                              void* d_out, int out_size, void* d_ws, size_t ws_size,
                              hipStream_t stream) {
    const float* z   = (const float*)d_in[0];
    const float* zpr = (const float*)d_in[1];
    float* out = (float*)d_out;
    u8*    q8  = (u8*)d_ws;                            // 1 MB
    float* nrm = (float*)((char*)d_ws + (1 << 20));    // 8 KB

    prep_kernel<<<256, 512, 0, stream>>>(z, zpr, q8, nrm);
    fused_kernel<<<512, 512, 0, stream>>>(q8, nrm, out);
}